// Round 5
// baseline (531.116 us; speedup 1.0000x reference)
//
#include <hip/hip_runtime.h>
#include <hip/hip_bf16.h>

// GCN encoder: x = emb[types]; x1 = relu(gcnconv(x,W1,b1)); out = gcnconv(x1,W2,b2)
// gcnconv: deg[i] = indeg(i)+1 (self loop); dis = rsqrt(deg);
//          out[i] = sum_{e:dst=i} (x[src_e]@W)*dis[src]*dis[i] + (x[i]@W)*dis[i]^2 + b
//
// Strategy (round 5):
//  - embW = emb @ W1 (1000x128, L2-resident): layer-1 messages gather 512B rows.
//  - CSR by dst; fill_k scatters ONLY csr_src (4B/edge, minimal line bouncing);
//    payload_k then builds a coalesced int4 {src,type,dis} stream per edge.
//  - agg kernels: one wave per node, zero LDS, max occupancy (latency-bound).
//  - gemm2: 8 rows/wave share each W2 ds_read_b128 ([k4][j] float4 LDS layout);
//    x broadcast via v_readlane (VALU), keeping the per-CU DS pipe nearly idle.
//    h2 written IN-PLACE into x1 rows (cols 0..63).

#define D1 128
#define D2 64

__device__ __forceinline__ float bcast(float v, int l) {
    return __int_as_float(__builtin_amdgcn_readlane(__float_as_int(v), l));
}

__global__ void count_k(const int* __restrict__ dst, int* __restrict__ cnt, int e) {
    int stride = gridDim.x * blockDim.x;
    for (int t = blockIdx.x * blockDim.x + threadIdx.x; t < e; t += stride)
        atomicAdd(&cnt[dst[t]], 1);
}

__global__ void dis_k(const int* __restrict__ cnt, float* __restrict__ dis, int n) {
    int stride = gridDim.x * blockDim.x;
    for (int t = blockIdx.x * blockDim.x + threadIdx.x; t < n; t += stride)
        dis[t] = rsqrtf((float)(cnt[t] + 1));
}

// ---- 3-kernel exclusive scan of cnt[] -> off[] ----
__global__ void scan1_k(const int* __restrict__ cnt, int* __restrict__ off,
                        int* __restrict__ bsum, int n) {
    __shared__ int tmp[256];
    int tid = threadIdx.x;
    int gid = blockIdx.x * 256 + tid;
    int v = (gid < n) ? cnt[gid] : 0;
    tmp[tid] = v;
    __syncthreads();
    for (int s = 1; s < 256; s <<= 1) {
        int a = (tid >= s) ? tmp[tid - s] : 0;
        __syncthreads();
        tmp[tid] += a;
        __syncthreads();
    }
    if (gid < n) off[gid] = tmp[tid] - v;           // exclusive
    if (tid == 255) bsum[blockIdx.x] = tmp[255];    // block total
}

__global__ void scan2_k(int* __restrict__ bsum, int nb) {
    __shared__ int tmp[1024];
    int tid = threadIdx.x;
    int v = (tid < nb) ? bsum[tid] : 0;
    tmp[tid] = v;
    __syncthreads();
    for (int s = 1; s < 1024; s <<= 1) {
        int a = (tid >= s) ? tmp[tid - s] : 0;
        __syncthreads();
        tmp[tid] += a;
        __syncthreads();
    }
    if (tid < nb) bsum[tid] = tmp[tid] - v;         // exclusive over blocks
}

__global__ void scan3_k(int* __restrict__ off, const int* __restrict__ bsum, int n) {
    int gid = blockIdx.x * 256 + threadIdx.x;
    if (gid < n) off[gid] += bsum[blockIdx.x];
}

// minimal scatter: only the 4B src index per edge
__global__ void fill_k(const int* __restrict__ src, const int* __restrict__ dst,
                       const int* __restrict__ off, int* __restrict__ cursor,
                       int* __restrict__ csr_src, int e) {
    int stride = gridDim.x * blockDim.x;
    for (int t = blockIdx.x * blockDim.x + threadIdx.x; t < e; t += stride) {
        int d = dst[t];
        int p = off[d] + atomicAdd(&cursor[d], 1);
        csr_src[p] = src[t];
    }
}

// coalesced payload build: {src, type[src], dis[src]} per CSR slot.
// gathers hit the L2-resident 400KB types/dis tables; write is streaming.
__global__ void payload_k(const int* __restrict__ csr_src,
                          const int* __restrict__ types,
                          const float* __restrict__ dis,
                          int4* __restrict__ csr_p, int e) {
    int stride = gridDim.x * blockDim.x;
    for (int t = blockIdx.x * blockDim.x + threadIdx.x; t < e; t += stride) {
        int s = csr_src[t];
        csr_p[t] = make_int4(s, types[s], __float_as_int(dis[s]), 0);
    }
}

// embW[r][j] = sum_k emb[r][k] * W1[k][j]   (ntypes x 128)
__global__ __launch_bounds__(128) void gemm_emb_k(const float* __restrict__ emb,
                                                  const float* __restrict__ W1,
                                                  float* __restrict__ embW, int ntypes) {
    __shared__ float w[D1 * D1];  // 64 KB
    for (int t = threadIdx.x; t < D1 * D1; t += 128) w[t] = W1[t];
    __syncthreads();
    int j = threadIdx.x;
    for (int r = blockIdx.x; r < ntypes; r += gridDim.x) {
        const float* er = emb + (size_t)r * D1;
        float acc = 0.f;
        #pragma unroll 8
        for (int k = 0; k < D1; ++k) acc = fmaf(er[k], w[k * D1 + j], acc);
        embW[(size_t)r * D1 + j] = acc;
    }
}

// layer-1 aggregation: ONE WAVE PER NODE. 2 sub-groups of 32 lanes; each sub
// handles one edge per iteration, lane holds float4 at feature (lane&31)*4.
__global__ __launch_bounds__(256) void agg1_k(const int* __restrict__ types,
                                              const int4* __restrict__ csr_p,
                                              const int* __restrict__ off,
                                              const int* __restrict__ cnt,
                                              const float* __restrict__ dis,
                                              const float* __restrict__ embW,
                                              const float* __restrict__ b1,
                                              float* __restrict__ x1, int n) {
    int i = (blockIdx.x * blockDim.x + threadIdx.x) >> 6;   // node = wave id
    if (i >= n) return;
    int lane = threadIdx.x & 63;
    int sub = lane >> 5;            // 0..1
    int fl = (lane & 31) << 2;      // feature base 0..124
    float disi = dis[i];
    int ti = types[i];
    int base = off[i], c = cnt[i];
    int total = c + 1;              // + self loop (virtual edge idx==c)
    float4 acc = make_float4(0.f, 0.f, 0.f, 0.f);
    for (int cb = 0; cb < total; cb += 64) {
        int idx = cb + lane;
        int t_l = 0;
        float c_l = 0.f;
        if (idx < c) {
            int4 q = csr_p[base + idx];
            t_l = q.y;
            c_l = disi * __int_as_float(q.z);
        } else if (idx == c) {
            t_l = ti;
            c_l = disi * disi;      // self loop
        }
        int m = min(64, total - cb);
        for (int k0 = 0; k0 < m; k0 += 2) {
            int k = k0 + sub;       // <= 63 always
            int t = __shfl(t_l, k);
            float cf = __shfl(c_l, k);  // 0 for out-of-range k
            float4 v = *(const float4*)(embW + (size_t)t * D1 + fl);
            acc.x = fmaf(v.x, cf, acc.x);
            acc.y = fmaf(v.y, cf, acc.y);
            acc.z = fmaf(v.z, cf, acc.z);
            acc.w = fmaf(v.w, cf, acc.w);
        }
    }
    // reduce the two sub-groups
    acc.x += __shfl_xor(acc.x, 32);
    acc.y += __shfl_xor(acc.y, 32);
    acc.z += __shfl_xor(acc.z, 32);
    acc.w += __shfl_xor(acc.w, 32);
    if (sub == 0) {
        float4 bv = ((const float4*)b1)[lane & 31];
        acc.x = fmaxf(acc.x + bv.x, 0.f);
        acc.y = fmaxf(acc.y + bv.y, 0.f);
        acc.z = fmaxf(acc.z + bv.z, 0.f);
        acc.w = fmaxf(acc.w + bv.w, 0.f);
        ((float4*)(x1 + (size_t)i * D1))[lane & 31] = acc;
    }
}

// h2 = x1 @ W2, written IN-PLACE into x1 row cols 0..63.
// One wave per 8 rows. W2 in LDS as float4 [k4][j]: per k4 ONE ds_read_b128
// (stride-16B, conflict-free) shared by 8 rows. x values broadcast from
// lane-held row registers via v_readlane (compile-time lane index, VALU pipe).
__global__ __launch_bounds__(256) void gemm2_k(float* __restrict__ x1,
                                               const float* __restrict__ W2, int n) {
    __shared__ float4 w2v[32 * 64];  // 32 KB
    {
        int j = threadIdx.x & 63;
        int k40 = threadIdx.x >> 6;
        for (int k4 = k40; k4 < 32; k4 += 4) {
            float4 v;
            v.x = W2[(k4 * 4 + 0) * D2 + j];
            v.y = W2[(k4 * 4 + 1) * D2 + j];
            v.z = W2[(k4 * 4 + 2) * D2 + j];
            v.w = W2[(k4 * 4 + 3) * D2 + j];
            w2v[k4 * 64 + j] = v;
        }
    }
    __syncthreads();
    int lane = threadIdx.x & 63;
    int gw = (blockIdx.x * blockDim.x + threadIdx.x) >> 6;  // global wave id
    int r0 = gw * 8;
    if (r0 >= n) return;
    float xlo[8], xhi[8], acc[8];
    #pragma unroll
    for (int r = 0; r < 8; ++r) {
        int rr = r0 + r;
        bool ok = rr < n;
        xlo[r] = ok ? x1[(size_t)rr * D1 + lane] : 0.f;
        xhi[r] = ok ? x1[(size_t)rr * D1 + 64 + lane] : 0.f;
        acc[r] = 0.f;
    }
    #pragma unroll
    for (int k4 = 0; k4 < 32; ++k4) {
        float4 wv = w2v[k4 * 64 + lane];
        #pragma unroll
        for (int r = 0; r < 8; ++r) {
            float xs = (k4 < 16) ? xlo[r] : xhi[r];
            acc[r] = fmaf(bcast(xs, (k4 * 4 + 0) & 63), wv.x, acc[r]);
            acc[r] = fmaf(bcast(xs, (k4 * 4 + 1) & 63), wv.y, acc[r]);
            acc[r] = fmaf(bcast(xs, (k4 * 4 + 2) & 63), wv.z, acc[r]);
            acc[r] = fmaf(bcast(xs, (k4 * 4 + 3) & 63), wv.w, acc[r]);
        }
    }
    #pragma unroll
    for (int r = 0; r < 8; ++r)
        if (r0 + r < n) x1[(size_t)(r0 + r) * D1 + lane] = acc[r];  // h2 row
}

// layer-2 aggregation: ONE WAVE PER NODE. 4 sub-groups of 16 lanes; each sub
// handles one edge per iteration, lane holds float4 at feature (lane&15)*4.
// h2 rows live at x1 + s*D1 (cols 0..63).
__global__ __launch_bounds__(256) void agg2_k(const int4* __restrict__ csr_p,
                                              const int* __restrict__ off,
                                              const int* __restrict__ cnt,
                                              const float* __restrict__ dis,
                                              const float* __restrict__ h2,
                                              const float* __restrict__ b2,
                                              float* __restrict__ out, int n) {
    int i = (blockIdx.x * blockDim.x + threadIdx.x) >> 6;   // node = wave id
    if (i >= n) return;
    int lane = threadIdx.x & 63;
    int sub = lane >> 4;            // 0..3
    int fl = (lane & 15) << 2;      // feature base 0..60
    float disi = dis[i];
    int base = off[i], c = cnt[i];
    int total = c + 1;              // + self loop (virtual edge idx==c)
    float4 acc = make_float4(0.f, 0.f, 0.f, 0.f);
    for (int cb = 0; cb < total; cb += 64) {
        int idx = cb + lane;
        int s_l = i;
        float c_l = 0.f;
        if (idx < c) {
            int4 q = csr_p[base + idx];
            s_l = q.x;
            c_l = disi * __int_as_float(q.z);
        } else if (idx == c) {
            c_l = disi * disi;      // self loop
        }
        int m = min(64, total - cb);
        for (int k0 = 0; k0 < m; k0 += 4) {
            int k = k0 + sub;       // <= 63 always
            int s = __shfl(s_l, k);
            float cf = __shfl(c_l, k);  // 0 for out-of-range k
            float4 v = *(const float4*)(h2 + (size_t)s * D1 + fl);
            acc.x = fmaf(v.x, cf, acc.x);
            acc.y = fmaf(v.y, cf, acc.y);
            acc.z = fmaf(v.z, cf, acc.z);
            acc.w = fmaf(v.w, cf, acc.w);
        }
    }
    // reduce the four sub-groups
    acc.x += __shfl_xor(acc.x, 16);
    acc.y += __shfl_xor(acc.y, 16);
    acc.z += __shfl_xor(acc.z, 16);
    acc.w += __shfl_xor(acc.w, 16);
    acc.x += __shfl_xor(acc.x, 32);
    acc.y += __shfl_xor(acc.y, 32);
    acc.z += __shfl_xor(acc.z, 32);
    acc.w += __shfl_xor(acc.w, 32);
    if (sub == 0) {
        float4 bv = ((const float4*)b2)[lane & 15];
        acc.x += bv.x;
        acc.y += bv.y;
        acc.z += bv.z;
        acc.w += bv.w;
        ((float4*)(out + (size_t)i * D2))[lane & 15] = acc;
    }
}

extern "C" void kernel_launch(void* const* d_in, const int* in_sizes, int n_in,
                              void* d_out, int out_size, void* d_ws, size_t ws_size,
                              hipStream_t stream) {
    const int* types = (const int*)d_in[0];
    const int* edges = (const int*)d_in[1];
    const float* emb = (const float*)d_in[2];
    const float* W1  = (const float*)d_in[3];
    const float* b1  = (const float*)d_in[4];
    const float* W2  = (const float*)d_in[5];
    const float* b2  = (const float*)d_in[6];
    float* out = (float*)d_out;

    const int n = in_sizes[0];
    const int e = in_sizes[1] / 2;
    const int ntypes = in_sizes[2] / D1;
    const int* src = edges;
    const int* dst = edges + e;

    // ---- workspace layout (256B aligned slabs), ~85 MB total ----
    char* p = (char*)d_ws;
    auto alloc = [&](size_t bytes) {
        char* r = p;
        p += (bytes + 255) & ~(size_t)255;
        return r;
    };
    int*   off     = (int*)  alloc((size_t)(n + 1) * 4);
    int*   cnt     = (int*)  alloc((size_t)n * 4);
    int*   cursor  = (int*)  alloc((size_t)n * 4);
    int*   bsum    = (int*)  alloc(1024 * 4);
    float* dis     = (float*)alloc((size_t)n * 4);
    int*   csr_src = (int*)  alloc((size_t)e * 4);
    int4*  csr_p   = (int4*) alloc((size_t)e * 16);
    float* embW    = (float*)alloc((size_t)ntypes * D1 * 4);
    float* x1      = (float*)alloc((size_t)n * D1 * 4);  // also holds h2 in cols 0..63
    (void)ws_size;

    hipMemsetAsync(cnt, 0, (size_t)n * 4, stream);
    hipMemsetAsync(cursor, 0, (size_t)n * 4, stream);

    // ---- degree / dis / CSR / payload ----
    count_k<<<2048, 256, 0, stream>>>(dst, cnt, e);
    dis_k<<<(n + 255) / 256, 256, 0, stream>>>(cnt, dis, n);
    int nb = (n + 255) / 256;   // 391 for N=100000 (must be <= 1024)
    scan1_k<<<nb, 256, 0, stream>>>(cnt, off, bsum, n);
    scan2_k<<<1, 1024, 0, stream>>>(bsum, nb);
    scan3_k<<<nb, 256, 0, stream>>>(off, bsum, n);
    fill_k<<<2048, 256, 0, stream>>>(src, dst, off, cursor, csr_src, e);
    payload_k<<<2048, 256, 0, stream>>>(csr_src, types, dis, csr_p, e);

    // ---- layer 1: embW = emb@W1; aggregate -> x1 (relu(agg + b1)) ----
    gemm_emb_k<<<256, 128, 0, stream>>>(emb, W1, embW, ntypes);
    int nwb = (n + 3) / 4;      // one wave per node, 4 waves per block
    agg1_k<<<nwb, 256, 0, stream>>>(types, csr_p, off, cnt, dis, embW, b1, x1, n);

    // ---- layer 2: h2 = x1@W2 in-place (8 rows/wave); aggregate h2 -> out ----
    int ngw = (n + 7) / 8;      // waves
    gemm2_k<<<(ngw + 3) / 4, 256, 0, stream>>>(x1, W2, n);
    agg2_k<<<nwb, 256, 0, stream>>>(csr_p, off, cnt, dis, x1, b2, out, n);
}

// Round 6
// 391.314 us; speedup vs baseline: 1.3573x; 1.3573x over previous
//
#include <hip/hip_runtime.h>
#include <hip/hip_bf16.h>

// GCN encoder: x = emb[types]; x1 = relu(gcnconv(x,W1,b1)); out = gcnconv(x1,W2,b2)
// gcnconv: deg[i] = indeg(i)+1 (self loop); dis = rsqrt(deg);
//          out[i] = sum_{e:dst=i} (x[src_e]@W)*dis[src]*dis[i] + (x[i]@W)*dis[i]^2 + b
//
// Strategy (round 6):
//  - Bucketed CSR build: partition edges into 512-node dst-buckets (LDS histograms,
//    chunked clustered writes), then per-bucket blocks build the CSR with ALL
//    per-node atomics in LDS. No global random atomics, no line bouncing.
//    Global node-offset scan falls out of bucket bases + LDS scans (scan1/2/3 gone).
//  - embW = emb @ W1 (1000x128, L2-resident): layer-1 messages gather 512B rows.
//  - agg kernels: one wave per node, zero LDS; 64-wide preload of (src,type) +
//    dis[src] gather, shfl-broadcast edge loop with float4 row gathers.
//  - gemm2: 8 rows/wave, W2 via ds_read_b128, x bcast via v_readlane; h2 in-place.

#define D1 128
#define D2 64
#define BSH 9            // bucket covers 512 nodes
#define BW  512
#define BMAX 256         // max buckets supported (n <= 131072)
#define TILE 2048        // edges per bpart block (8 per thread)

__device__ __forceinline__ float bcast(float v, int l) {
    return __int_as_float(__builtin_amdgcn_readlane(__float_as_int(v), l));
}

// ---- bucket histogram (LDS-aggregated) ----
__global__ __launch_bounds__(256) void bhist_k(const int* __restrict__ dst,
                                               int* __restrict__ bcnt, int e) {
    __shared__ int h[BMAX];
    if (threadIdx.x < BMAX) h[threadIdx.x] = 0;
    __syncthreads();
    int stride = gridDim.x * blockDim.x;
    for (int t = blockIdx.x * blockDim.x + threadIdx.x; t < e; t += stride)
        atomicAdd(&h[dst[t] >> BSH], 1);
    __syncthreads();
    if (threadIdx.x < BMAX && h[threadIdx.x])
        atomicAdd(&bcnt[threadIdx.x], h[threadIdx.x]);
}

// ---- bucket base scan (one block) ----
__global__ void bscan_k(const int* __restrict__ bcnt, int* __restrict__ bbase,
                        int* __restrict__ bcur, int nb) {
    __shared__ int tmp[BMAX];
    int tid = threadIdx.x;          // 256 threads
    int v = (tid < nb) ? bcnt[tid] : 0;
    tmp[tid] = v;
    __syncthreads();
    for (int s = 1; s < BMAX; s <<= 1) {
        int a = (tid >= s) ? tmp[tid - s] : 0;
        __syncthreads();
        tmp[tid] += a;
        __syncthreads();
    }
    if (tid < nb) { int ex = tmp[tid] - v; bbase[tid] = ex; bcur[tid] = ex; }
}

// ---- partition edges into bucket regions (chunk-reserved clustered writes) ----
__global__ __launch_bounds__(256) void bpart_k(const int* __restrict__ src,
                                               const int* __restrict__ dst,
                                               int* __restrict__ bcur,
                                               int2* __restrict__ ebuf, int e) {
    __shared__ int hist[BMAX];
    __shared__ int chunk[BMAX];
    __shared__ int lcur[BMAX];
    int tid = threadIdx.x;
    int base = blockIdx.x * TILE;
    if (tid < BMAX) { hist[tid] = 0; lcur[tid] = 0; }
    __syncthreads();
    int s8[8], d8[8], b8[8];
    #pragma unroll
    for (int i = 0; i < 8; ++i) {
        int t = base + i * 256 + tid;
        if (t < e) {
            s8[i] = src[t]; d8[i] = dst[t]; b8[i] = d8[i] >> BSH;
            atomicAdd(&hist[b8[i]], 1);
        } else b8[i] = -1;
    }
    __syncthreads();
    if (tid < BMAX && hist[tid]) chunk[tid] = atomicAdd(&bcur[tid], hist[tid]);
    __syncthreads();
    #pragma unroll
    for (int i = 0; i < 8; ++i) {
        if (b8[i] >= 0) {
            int r = atomicAdd(&lcur[b8[i]], 1);
            ebuf[chunk[b8[i]] + r] = make_int2(s8[i], d8[i]);
        }
    }
}

// ---- per-bucket CSR build: LDS count + scan + cursor; emits cnt/off/csr ----
__global__ __launch_bounds__(512) void bcsr_k(const int2* __restrict__ ebuf,
                                              const int* __restrict__ bbase,
                                              const int* __restrict__ bcnt,
                                              const int* __restrict__ types,
                                              int* __restrict__ cnt,
                                              int* __restrict__ off,
                                              int2* __restrict__ csr, int n) {
    __shared__ int lcnt[BW];
    __shared__ int lsc[BW];
    __shared__ int lcur[BW];
    int b = blockIdx.x;
    int d0 = b << BSH;
    int tid = threadIdx.x;
    lcnt[tid] = 0; lcur[tid] = 0;
    __syncthreads();
    int ebase = bbase[b], ecnt = bcnt[b];
    for (int t = tid; t < ecnt; t += BW)
        atomicAdd(&lcnt[ebuf[ebase + t].y - d0], 1);
    __syncthreads();
    int v = lcnt[tid];
    lsc[tid] = v;
    __syncthreads();
    for (int s = 1; s < BW; s <<= 1) {
        int a = (tid >= s) ? lsc[tid - s] : 0;
        __syncthreads();
        lsc[tid] += a;
        __syncthreads();
    }
    int ex = lsc[tid] - v;          // exclusive within bucket
    int node = d0 + tid;
    if (node < n) { cnt[node] = v; off[node] = ebase + ex; }
    __syncthreads();
    lsc[tid] = ex;
    __syncthreads();
    for (int t = tid; t < ecnt; t += BW) {
        int2 q = ebuf[ebase + t];
        int l = q.y - d0;
        int r = atomicAdd(&lcur[l], 1);
        csr[ebase + lsc[l] + r] = make_int2(q.x, types[q.x]);
    }
}

__global__ void dis_k(const int* __restrict__ cnt, float* __restrict__ dis, int n) {
    int stride = gridDim.x * blockDim.x;
    for (int t = blockIdx.x * blockDim.x + threadIdx.x; t < n; t += stride)
        dis[t] = rsqrtf((float)(cnt[t] + 1));
}

// embW[r][j] = sum_k emb[r][k] * W1[k][j]   (ntypes x 128)
__global__ __launch_bounds__(128) void gemm_emb_k(const float* __restrict__ emb,
                                                  const float* __restrict__ W1,
                                                  float* __restrict__ embW, int ntypes) {
    __shared__ float w[D1 * D1];  // 64 KB
    for (int t = threadIdx.x; t < D1 * D1; t += 128) w[t] = W1[t];
    __syncthreads();
    int j = threadIdx.x;
    for (int r = blockIdx.x; r < ntypes; r += gridDim.x) {
        const float* er = emb + (size_t)r * D1;
        float acc = 0.f;
        #pragma unroll 8
        for (int k = 0; k < D1; ++k) acc = fmaf(er[k], w[k * D1 + j], acc);
        embW[(size_t)r * D1 + j] = acc;
    }
}

// layer-1 aggregation: ONE WAVE PER NODE. 2 sub-groups of 32 lanes; each sub
// handles one edge per iteration, lane holds float4 at feature (lane&31)*4.
__global__ __launch_bounds__(256) void agg1_k(const int* __restrict__ types,
                                              const int2* __restrict__ csr,
                                              const int* __restrict__ off,
                                              const int* __restrict__ cnt,
                                              const float* __restrict__ dis,
                                              const float* __restrict__ embW,
                                              const float* __restrict__ b1,
                                              float* __restrict__ x1, int n) {
    int i = (blockIdx.x * blockDim.x + threadIdx.x) >> 6;   // node = wave id
    if (i >= n) return;
    int lane = threadIdx.x & 63;
    int sub = lane >> 5;            // 0..1
    int fl = (lane & 31) << 2;      // feature base 0..124
    float disi = dis[i];
    int ti = types[i];
    int base = off[i], c = cnt[i];
    int total = c + 1;              // + self loop (virtual edge idx==c)
    float4 acc = make_float4(0.f, 0.f, 0.f, 0.f);
    for (int cb = 0; cb < total; cb += 64) {
        int idx = cb + lane;
        int t_l = 0;
        float c_l = 0.f;
        if (idx < c) {
            int2 q = csr[base + idx];
            t_l = q.y;
            c_l = disi * dis[q.x];
        } else if (idx == c) {
            t_l = ti;
            c_l = disi * disi;      // self loop
        }
        int m = min(64, total - cb);
        for (int k0 = 0; k0 < m; k0 += 2) {
            int k = k0 + sub;       // <= 63 always
            int t = __shfl(t_l, k);
            float cf = __shfl(c_l, k);  // 0 for out-of-range k
            float4 v = *(const float4*)(embW + (size_t)t * D1 + fl);
            acc.x = fmaf(v.x, cf, acc.x);
            acc.y = fmaf(v.y, cf, acc.y);
            acc.z = fmaf(v.z, cf, acc.z);
            acc.w = fmaf(v.w, cf, acc.w);
        }
    }
    acc.x += __shfl_xor(acc.x, 32);
    acc.y += __shfl_xor(acc.y, 32);
    acc.z += __shfl_xor(acc.z, 32);
    acc.w += __shfl_xor(acc.w, 32);
    if (sub == 0) {
        float4 bv = ((const float4*)b1)[lane & 31];
        acc.x = fmaxf(acc.x + bv.x, 0.f);
        acc.y = fmaxf(acc.y + bv.y, 0.f);
        acc.z = fmaxf(acc.z + bv.z, 0.f);
        acc.w = fmaxf(acc.w + bv.w, 0.f);
        ((float4*)(x1 + (size_t)i * D1))[lane & 31] = acc;
    }
}

// h2 = x1 @ W2, written IN-PLACE into x1 row cols 0..63.
// One wave per 8 rows; W2 staged as float4 [k4][j] (ds_read_b128, conflict-free);
// x broadcast via v_readlane (VALU pipe, not DS).
__global__ __launch_bounds__(256) void gemm2_k(float* __restrict__ x1,
                                               const float* __restrict__ W2, int n) {
    __shared__ float4 w2v[32 * 64];  // 32 KB
    {
        int j = threadIdx.x & 63;
        int k40 = threadIdx.x >> 6;
        for (int k4 = k40; k4 < 32; k4 += 4) {
            float4 v;
            v.x = W2[(k4 * 4 + 0) * D2 + j];
            v.y = W2[(k4 * 4 + 1) * D2 + j];
            v.z = W2[(k4 * 4 + 2) * D2 + j];
            v.w = W2[(k4 * 4 + 3) * D2 + j];
            w2v[k4 * 64 + j] = v;
        }
    }
    __syncthreads();
    int lane = threadIdx.x & 63;
    int gw = (blockIdx.x * blockDim.x + threadIdx.x) >> 6;  // global wave id
    int r0 = gw * 8;
    if (r0 >= n) return;
    float xlo[8], xhi[8], acc[8];
    #pragma unroll
    for (int r = 0; r < 8; ++r) {
        int rr = r0 + r;
        bool ok = rr < n;
        xlo[r] = ok ? x1[(size_t)rr * D1 + lane] : 0.f;
        xhi[r] = ok ? x1[(size_t)rr * D1 + 64 + lane] : 0.f;
        acc[r] = 0.f;
    }
    #pragma unroll
    for (int k4 = 0; k4 < 32; ++k4) {
        float4 wv = w2v[k4 * 64 + lane];
        #pragma unroll
        for (int r = 0; r < 8; ++r) {
            float xs = (k4 < 16) ? xlo[r] : xhi[r];
            acc[r] = fmaf(bcast(xs, (k4 * 4 + 0) & 63), wv.x, acc[r]);
            acc[r] = fmaf(bcast(xs, (k4 * 4 + 1) & 63), wv.y, acc[r]);
            acc[r] = fmaf(bcast(xs, (k4 * 4 + 2) & 63), wv.z, acc[r]);
            acc[r] = fmaf(bcast(xs, (k4 * 4 + 3) & 63), wv.w, acc[r]);
        }
    }
    #pragma unroll
    for (int r = 0; r < 8; ++r)
        if (r0 + r < n) x1[(size_t)(r0 + r) * D1 + lane] = acc[r];  // h2 row
}

// layer-2 aggregation: ONE WAVE PER NODE. 4 sub-groups of 16 lanes; each sub
// handles one edge per iteration, lane holds float4 at feature (lane&15)*4.
// h2 rows live at x1 + s*D1 (cols 0..63).
__global__ __launch_bounds__(256) void agg2_k(const int2* __restrict__ csr,
                                              const int* __restrict__ off,
                                              const int* __restrict__ cnt,
                                              const float* __restrict__ dis,
                                              const float* __restrict__ h2,
                                              const float* __restrict__ b2,
                                              float* __restrict__ out, int n) {
    int i = (blockIdx.x * blockDim.x + threadIdx.x) >> 6;   // node = wave id
    if (i >= n) return;
    int lane = threadIdx.x & 63;
    int sub = lane >> 4;            // 0..3
    int fl = (lane & 15) << 2;      // feature base 0..60
    float disi = dis[i];
    int base = off[i], c = cnt[i];
    int total = c + 1;              // + self loop (virtual edge idx==c)
    float4 acc = make_float4(0.f, 0.f, 0.f, 0.f);
    for (int cb = 0; cb < total; cb += 64) {
        int idx = cb + lane;
        int s_l = i;
        float c_l = 0.f;
        if (idx < c) {
            int2 q = csr[base + idx];
            s_l = q.x;
            c_l = disi * dis[q.x];
        } else if (idx == c) {
            c_l = disi * disi;      // self loop
        }
        int m = min(64, total - cb);
        for (int k0 = 0; k0 < m; k0 += 4) {
            int k = k0 + sub;       // <= 63 always
            int s = __shfl(s_l, k);
            float cf = __shfl(c_l, k);  // 0 for out-of-range k
            float4 v = *(const float4*)(h2 + (size_t)s * D1 + fl);
            acc.x = fmaf(v.x, cf, acc.x);
            acc.y = fmaf(v.y, cf, acc.y);
            acc.z = fmaf(v.z, cf, acc.z);
            acc.w = fmaf(v.w, cf, acc.w);
        }
    }
    acc.x += __shfl_xor(acc.x, 16);
    acc.y += __shfl_xor(acc.y, 16);
    acc.z += __shfl_xor(acc.z, 16);
    acc.w += __shfl_xor(acc.w, 16);
    acc.x += __shfl_xor(acc.x, 32);
    acc.y += __shfl_xor(acc.y, 32);
    acc.z += __shfl_xor(acc.z, 32);
    acc.w += __shfl_xor(acc.w, 32);
    if (sub == 0) {
        float4 bv = ((const float4*)b2)[lane & 15];
        acc.x += bv.x;
        acc.y += bv.y;
        acc.z += bv.z;
        acc.w += bv.w;
        ((float4*)(out + (size_t)i * D2))[lane & 15] = acc;
    }
}

extern "C" void kernel_launch(void* const* d_in, const int* in_sizes, int n_in,
                              void* d_out, int out_size, void* d_ws, size_t ws_size,
                              hipStream_t stream) {
    const int* types = (const int*)d_in[0];
    const int* edges = (const int*)d_in[1];
    const float* emb = (const float*)d_in[2];
    const float* W1  = (const float*)d_in[3];
    const float* b1  = (const float*)d_in[4];
    const float* W2  = (const float*)d_in[5];
    const float* b2  = (const float*)d_in[6];
    float* out = (float*)d_out;

    const int n = in_sizes[0];
    const int e = in_sizes[1] / 2;
    const int ntypes = in_sizes[2] / D1;
    const int* src = edges;
    const int* dst = edges + e;
    const int nb = (n + BW - 1) >> BSH;   // 196 buckets for n=100000 (<= BMAX)

    // ---- workspace layout (256B aligned slabs), ~80 MB total ----
    char* p = (char*)d_ws;
    auto alloc = [&](size_t bytes) {
        char* r = p;
        p += (bytes + 255) & ~(size_t)255;
        return r;
    };
    int*   bcnt  = (int*)  alloc(BMAX * 4);
    int*   bbase = (int*)  alloc(BMAX * 4);
    int*   bcur  = (int*)  alloc(BMAX * 4);
    int*   cnt   = (int*)  alloc((size_t)n * 4);
    int*   off   = (int*)  alloc((size_t)n * 4);
    float* dis   = (float*)alloc((size_t)n * 4);
    int2*  ebuf  = (int2*) alloc((size_t)e * 8);
    int2*  csr   = (int2*) alloc((size_t)e * 8);
    float* embW  = (float*)alloc((size_t)ntypes * D1 * 4);
    float* x1    = (float*)alloc((size_t)n * D1 * 4);  // also holds h2 in cols 0..63
    (void)ws_size;

    hipMemsetAsync(bcnt, 0, BMAX * 4, stream);

    // ---- bucketed CSR build ----
    bhist_k<<<512, 256, 0, stream>>>(dst, bcnt, e);
    bscan_k<<<1, BMAX, 0, stream>>>(bcnt, bbase, bcur, nb);
    bpart_k<<<(e + TILE - 1) / TILE, 256, 0, stream>>>(src, dst, bcur, ebuf, e);
    bcsr_k<<<nb, BW, 0, stream>>>(ebuf, bbase, bcnt, types, cnt, off, csr, n);
    dis_k<<<(n + 255) / 256, 256, 0, stream>>>(cnt, dis, n);

    // ---- layer 1: embW = emb@W1; aggregate -> x1 (relu(agg + b1)) ----
    gemm_emb_k<<<256, 128, 0, stream>>>(emb, W1, embW, ntypes);
    int nwb = (n + 3) / 4;      // one wave per node, 4 waves per block
    agg1_k<<<nwb, 256, 0, stream>>>(types, csr, off, cnt, dis, embW, b1, x1, n);

    // ---- layer 2: h2 = x1@W2 in-place (8 rows/wave); aggregate h2 -> out ----
    int ngw = (n + 7) / 8;
    gemm2_k<<<(ngw + 3) / 4, 256, 0, stream>>>(x1, W2, n);
    agg2_k<<<nwb, 256, 0, stream>>>(csr, off, cnt, dis, x1, b2, out, n);
}

// Round 7
// 310.574 us; speedup vs baseline: 1.7101x; 1.2600x over previous
//
#include <hip/hip_runtime.h>
#include <hip/hip_bf16.h>

// GCN encoder: x = emb[types]; x1 = relu(gcnconv(x,W1,b1)); out = gcnconv(x1,W2,b2)
// gcnconv: deg[i] = indeg(i)+1 (self loop); dis = rsqrt(deg);
//          out[i] = sum_{e:dst=i} (x[src_e]@W)*dis[src]*dis[i] + (x[i]@W)*dis[i]^2 + b
//
// Strategy (round 7):
//  - Bucketed CSR build (all fine-grained atomics in LDS; no line bouncing).
//  - embW = emb @ W1 (1000x128, L2-resident): layer-1 messages gather 512B rows.
//  - agg kernels: one wave per node, zero LDS, shfl-broadcast edge loop.
//  - gemm2: MFMA (16x16x32 bf16) with split-bf16 fp32 emulation
//    (xh@Wh + xl@Wh + xh@Wl; xl@Wl ~2^-16 dropped). W2 pre-fragmented to
//    bf16 hi/lo tables so B-frags are single b128 loads. h2 in-place in x1.

#define D1 128
#define D2 64
#define BSH 9            // bucket covers 512 nodes
#define BW  512
#define BMAX 256         // max buckets supported (n <= 131072)
#define TILE 2048        // edges per bpart block (8 per thread)

typedef __attribute__((ext_vector_type(8))) short short8v;
typedef __attribute__((ext_vector_type(4))) float f32x4;

__device__ __forceinline__ short bf16_hi(float x) {
    return (short)(__float_as_uint(x) >> 16);
}
__device__ __forceinline__ float hi_f(float x) {
    return __uint_as_float(__float_as_uint(x) & 0xFFFF0000u);
}
__device__ __forceinline__ short bf16_rne(float x) {
    unsigned u = __float_as_uint(x);
    return (short)((u + 0x7FFFu + ((u >> 16) & 1u)) >> 16);
}

// ---- bucket histogram (LDS-aggregated) ----
__global__ __launch_bounds__(256) void bhist_k(const int* __restrict__ dst,
                                               int* __restrict__ bcnt, int e) {
    __shared__ int h[BMAX];
    if (threadIdx.x < BMAX) h[threadIdx.x] = 0;
    __syncthreads();
    int stride = gridDim.x * blockDim.x;
    for (int t = blockIdx.x * blockDim.x + threadIdx.x; t < e; t += stride)
        atomicAdd(&h[dst[t] >> BSH], 1);
    __syncthreads();
    if (threadIdx.x < BMAX && h[threadIdx.x])
        atomicAdd(&bcnt[threadIdx.x], h[threadIdx.x]);
}

// ---- bucket base scan (one block) ----
__global__ void bscan_k(const int* __restrict__ bcnt, int* __restrict__ bbase,
                        int* __restrict__ bcur, int nb) {
    __shared__ int tmp[BMAX];
    int tid = threadIdx.x;          // 256 threads
    int v = (tid < nb) ? bcnt[tid] : 0;
    tmp[tid] = v;
    __syncthreads();
    for (int s = 1; s < BMAX; s <<= 1) {
        int a = (tid >= s) ? tmp[tid - s] : 0;
        __syncthreads();
        tmp[tid] += a;
        __syncthreads();
    }
    if (tid < nb) { int ex = tmp[tid] - v; bbase[tid] = ex; bcur[tid] = ex; }
}

// ---- partition edges into bucket regions (chunk-reserved clustered writes) ----
__global__ __launch_bounds__(256) void bpart_k(const int* __restrict__ src,
                                               const int* __restrict__ dst,
                                               int* __restrict__ bcur,
                                               int2* __restrict__ ebuf, int e) {
    __shared__ int hist[BMAX];
    __shared__ int chunk[BMAX];
    __shared__ int lcur[BMAX];
    int tid = threadIdx.x;
    int base = blockIdx.x * TILE;
    if (tid < BMAX) { hist[tid] = 0; lcur[tid] = 0; }
    __syncthreads();
    int s8[8], d8[8], b8[8];
    #pragma unroll
    for (int i = 0; i < 8; ++i) {
        int t = base + i * 256 + tid;
        if (t < e) {
            s8[i] = src[t]; d8[i] = dst[t]; b8[i] = d8[i] >> BSH;
            atomicAdd(&hist[b8[i]], 1);
        } else b8[i] = -1;
    }
    __syncthreads();
    if (tid < BMAX && hist[tid]) chunk[tid] = atomicAdd(&bcur[tid], hist[tid]);
    __syncthreads();
    #pragma unroll
    for (int i = 0; i < 8; ++i) {
        if (b8[i] >= 0) {
            int r = atomicAdd(&lcur[b8[i]], 1);
            ebuf[chunk[b8[i]] + r] = make_int2(s8[i], d8[i]);
        }
    }
}

// ---- per-bucket CSR build: LDS count + scan + cursor; emits cnt/off/csr ----
__global__ __launch_bounds__(512) void bcsr_k(const int2* __restrict__ ebuf,
                                              const int* __restrict__ bbase,
                                              const int* __restrict__ bcnt,
                                              const int* __restrict__ types,
                                              int* __restrict__ cnt,
                                              int* __restrict__ off,
                                              int2* __restrict__ csr, int n) {
    __shared__ int lcnt[BW];
    __shared__ int lsc[BW];
    __shared__ int lcur[BW];
    int b = blockIdx.x;
    int d0 = b << BSH;
    int tid = threadIdx.x;
    lcnt[tid] = 0; lcur[tid] = 0;
    __syncthreads();
    int ebase = bbase[b], ecnt = bcnt[b];
    for (int t = tid; t < ecnt; t += BW)
        atomicAdd(&lcnt[ebuf[ebase + t].y - d0], 1);
    __syncthreads();
    int v = lcnt[tid];
    lsc[tid] = v;
    __syncthreads();
    for (int s = 1; s < BW; s <<= 1) {
        int a = (tid >= s) ? lsc[tid - s] : 0;
        __syncthreads();
        lsc[tid] += a;
        __syncthreads();
    }
    int ex = lsc[tid] - v;          // exclusive within bucket
    int node = d0 + tid;
    if (node < n) { cnt[node] = v; off[node] = ebase + ex; }
    __syncthreads();
    lsc[tid] = ex;
    __syncthreads();
    for (int t = tid; t < ecnt; t += BW) {
        int2 q = ebuf[ebase + t];
        int l = q.y - d0;
        int r = atomicAdd(&lcur[l], 1);
        csr[ebase + lsc[l] + r] = make_int2(q.x, types[q.x]);
    }
}

__global__ void dis_k(const int* __restrict__ cnt, float* __restrict__ dis, int n) {
    int stride = gridDim.x * blockDim.x;
    for (int t = blockIdx.x * blockDim.x + threadIdx.x; t < n; t += stride)
        dis[t] = rsqrtf((float)(cnt[t] + 1));
}

// ---- W2 -> frag-ordered bf16 hi/lo tables ----
// frag (ct,kb), lane l (kq=l>>4, col=l&15), elem j holds
// W2[kb*32 + kq*8 + j][ct*16 + col]; stored at ((ct*4+kb)*64 + l)*8 + j.
__global__ void w2prep_k(const float* __restrict__ W2,
                         short* __restrict__ w2h, short* __restrict__ w2l) {
    int t = blockIdx.x * blockDim.x + threadIdx.x;   // t = k*64 + c
    if (t >= D1 * D2) return;
    int k = t >> 6, c = t & 63;
    float v = W2[t];
    int ct = c >> 4, kb = k >> 5;
    int l = (((k >> 3) & 3) << 4) | (c & 15);
    int j = k & 7;
    int idx = (((ct << 2) | kb) * 64 + l) * 8 + j;
    w2h[idx] = bf16_hi(v);
    w2l[idx] = bf16_rne(v - hi_f(v));
}

// embW[r][j] = sum_k emb[r][k] * W1[k][j]   (ntypes x 128)
__global__ __launch_bounds__(128) void gemm_emb_k(const float* __restrict__ emb,
                                                  const float* __restrict__ W1,
                                                  float* __restrict__ embW, int ntypes) {
    __shared__ float w[D1 * D1];  // 64 KB
    for (int t = threadIdx.x; t < D1 * D1; t += 128) w[t] = W1[t];
    __syncthreads();
    int j = threadIdx.x;
    for (int r = blockIdx.x; r < ntypes; r += gridDim.x) {
        const float* er = emb + (size_t)r * D1;
        float acc = 0.f;
        #pragma unroll 8
        for (int k = 0; k < D1; ++k) acc = fmaf(er[k], w[k * D1 + j], acc);
        embW[(size_t)r * D1 + j] = acc;
    }
}

// layer-1 aggregation: ONE WAVE PER NODE. 2 sub-groups of 32 lanes; each sub
// handles one edge per iteration, lane holds float4 at feature (lane&31)*4.
__global__ __launch_bounds__(256) void agg1_k(const int* __restrict__ types,
                                              const int2* __restrict__ csr,
                                              const int* __restrict__ off,
                                              const int* __restrict__ cnt,
                                              const float* __restrict__ dis,
                                              const float* __restrict__ embW,
                                              const float* __restrict__ b1,
                                              float* __restrict__ x1, int n) {
    int i = (blockIdx.x * blockDim.x + threadIdx.x) >> 6;   // node = wave id
    if (i >= n) return;
    int lane = threadIdx.x & 63;
    int sub = lane >> 5;            // 0..1
    int fl = (lane & 31) << 2;      // feature base 0..124
    float disi = dis[i];
    int ti = types[i];
    int base = off[i], c = cnt[i];
    int total = c + 1;              // + self loop (virtual edge idx==c)
    float4 acc = make_float4(0.f, 0.f, 0.f, 0.f);
    for (int cb = 0; cb < total; cb += 64) {
        int idx = cb + lane;
        int t_l = 0;
        float c_l = 0.f;
        if (idx < c) {
            int2 q = csr[base + idx];
            t_l = q.y;
            c_l = disi * dis[q.x];
        } else if (idx == c) {
            t_l = ti;
            c_l = disi * disi;      // self loop
        }
        int m = min(64, total - cb);
        for (int k0 = 0; k0 < m; k0 += 2) {
            int k = k0 + sub;       // <= 63 always
            int t = __shfl(t_l, k);
            float cf = __shfl(c_l, k);  // 0 for out-of-range k
            float4 v = *(const float4*)(embW + (size_t)t * D1 + fl);
            acc.x = fmaf(v.x, cf, acc.x);
            acc.y = fmaf(v.y, cf, acc.y);
            acc.z = fmaf(v.z, cf, acc.z);
            acc.w = fmaf(v.w, cf, acc.w);
        }
    }
    acc.x += __shfl_xor(acc.x, 32);
    acc.y += __shfl_xor(acc.y, 32);
    acc.z += __shfl_xor(acc.z, 32);
    acc.w += __shfl_xor(acc.w, 32);
    if (sub == 0) {
        float4 bv = ((const float4*)b1)[lane & 31];
        acc.x = fmaxf(acc.x + bv.x, 0.f);
        acc.y = fmaxf(acc.y + bv.y, 0.f);
        acc.z = fmaxf(acc.z + bv.z, 0.f);
        acc.w = fmaxf(acc.w + bv.w, 0.f);
        ((float4*)(x1 + (size_t)i * D1))[lane & 31] = acc;
    }
}

// h2 = x1 @ W2 via MFMA, written IN-PLACE into x1 row cols 0..63.
// One wave per 16 rows. A-frag: lane holds row=lane&15, k=kb*32+(lane>>4)*8+j.
// B-frags: one b128 load from frag-ordered tables. Split-bf16 fp32 emulation:
// xh@Wh + xl@Wh + xh@Wl (xl@Wl ~2^-16 dropped). D: col=lane&15, row=(lane>>4)*4+v.
__global__ __launch_bounds__(256) void gemm2_k(float* __restrict__ x1,
                                               const short* __restrict__ w2h,
                                               const short* __restrict__ w2l, int n) {
    int gw = (blockIdx.x * blockDim.x + threadIdx.x) >> 6;  // global wave id
    int lane = threadIdx.x & 63;
    int r0 = gw << 4;
    if (r0 >= n) return;
    int row = r0 + (lane & 15);
    int kq = lane >> 4;             // 0..3
    bool ok = row < n;
    const float* xr = x1 + (size_t)row * D1 + kq * 8;
    short8v ah[4], al[4];
    #pragma unroll
    for (int kb = 0; kb < 4; ++kb) {
        float4 v0, v1;
        if (ok) {
            v0 = *(const float4*)(xr + kb * 32);
            v1 = *(const float4*)(xr + kb * 32 + 4);
        } else {
            v0 = make_float4(0.f, 0.f, 0.f, 0.f);
            v1 = v0;
        }
        float xv[8] = {v0.x, v0.y, v0.z, v0.w, v1.x, v1.y, v1.z, v1.w};
        #pragma unroll
        for (int j = 0; j < 8; ++j) {
            ah[kb][j] = bf16_hi(xv[j]);
            al[kb][j] = bf16_rne(xv[j] - hi_f(xv[j]));
        }
    }
    const short8v* w2hv = (const short8v*)w2h;
    const short8v* w2lv = (const short8v*)w2l;
    #pragma unroll
    for (int ct = 0; ct < 4; ++ct) {
        f32x4 acc = {0.f, 0.f, 0.f, 0.f};
        #pragma unroll
        for (int kb = 0; kb < 4; ++kb) {
            short8v bh = w2hv[(ct * 4 + kb) * 64 + lane];
            short8v bl = w2lv[(ct * 4 + kb) * 64 + lane];
            acc = __builtin_amdgcn_mfma_f32_16x16x32_bf16(ah[kb], bh, acc, 0, 0, 0);
            acc = __builtin_amdgcn_mfma_f32_16x16x32_bf16(al[kb], bh, acc, 0, 0, 0);
            acc = __builtin_amdgcn_mfma_f32_16x16x32_bf16(ah[kb], bl, acc, 0, 0, 0);
        }
        #pragma unroll
        for (int v = 0; v < 4; ++v) {
            int orow = r0 + (lane >> 4) * 4 + v;
            if (orow < n)
                x1[(size_t)orow * D1 + ct * 16 + (lane & 15)] = acc[v];
        }
    }
}

// layer-2 aggregation: ONE WAVE PER NODE. 4 sub-groups of 16 lanes; each sub
// handles one edge per iteration, lane holds float4 at feature (lane&15)*4.
// h2 rows live at x1 + s*D1 (cols 0..63).
__global__ __launch_bounds__(256) void agg2_k(const int2* __restrict__ csr,
                                              const int* __restrict__ off,
                                              const int* __restrict__ cnt,
                                              const float* __restrict__ dis,
                                              const float* __restrict__ h2,
                                              const float* __restrict__ b2,
                                              float* __restrict__ out, int n) {
    int i = (blockIdx.x * blockDim.x + threadIdx.x) >> 6;   // node = wave id
    if (i >= n) return;
    int lane = threadIdx.x & 63;
    int sub = lane >> 4;            // 0..3
    int fl = (lane & 15) << 2;      // feature base 0..60
    float disi = dis[i];
    int base = off[i], c = cnt[i];
    int total = c + 1;              // + self loop (virtual edge idx==c)
    float4 acc = make_float4(0.f, 0.f, 0.f, 0.f);
    for (int cb = 0; cb < total; cb += 64) {
        int idx = cb + lane;
        int s_l = i;
        float c_l = 0.f;
        if (idx < c) {
            int2 q = csr[base + idx];
            s_l = q.x;
            c_l = disi * dis[q.x];
        } else if (idx == c) {
            c_l = disi * disi;      // self loop
        }
        int m = min(64, total - cb);
        for (int k0 = 0; k0 < m; k0 += 4) {
            int k = k0 + sub;       // <= 63 always
            int s = __shfl(s_l, k);
            float cf = __shfl(c_l, k);  // 0 for out-of-range k
            float4 v = *(const float4*)(h2 + (size_t)s * D1 + fl);
            acc.x = fmaf(v.x, cf, acc.x);
            acc.y = fmaf(v.y, cf, acc.y);
            acc.z = fmaf(v.z, cf, acc.z);
            acc.w = fmaf(v.w, cf, acc.w);
        }
    }
    acc.x += __shfl_xor(acc.x, 16);
    acc.y += __shfl_xor(acc.y, 16);
    acc.z += __shfl_xor(acc.z, 16);
    acc.w += __shfl_xor(acc.w, 16);
    acc.x += __shfl_xor(acc.x, 32);
    acc.y += __shfl_xor(acc.y, 32);
    acc.z += __shfl_xor(acc.z, 32);
    acc.w += __shfl_xor(acc.w, 32);
    if (sub == 0) {
        float4 bv = ((const float4*)b2)[lane & 15];
        acc.x += bv.x;
        acc.y += bv.y;
        acc.z += bv.z;
        acc.w += bv.w;
        ((float4*)(out + (size_t)i * D2))[lane & 15] = acc;
    }
}

extern "C" void kernel_launch(void* const* d_in, const int* in_sizes, int n_in,
                              void* d_out, int out_size, void* d_ws, size_t ws_size,
                              hipStream_t stream) {
    const int* types = (const int*)d_in[0];
    const int* edges = (const int*)d_in[1];
    const float* emb = (const float*)d_in[2];
    const float* W1  = (const float*)d_in[3];
    const float* b1  = (const float*)d_in[4];
    const float* W2  = (const float*)d_in[5];
    const float* b2  = (const float*)d_in[6];
    float* out = (float*)d_out;

    const int n = in_sizes[0];
    const int e = in_sizes[1] / 2;
    const int ntypes = in_sizes[2] / D1;
    const int* src = edges;
    const int* dst = edges + e;
    const int nb = (n + BW - 1) >> BSH;   // 196 buckets for n=100000 (<= BMAX)

    // ---- workspace layout (256B aligned slabs), ~80 MB total ----
    char* p = (char*)d_ws;
    auto alloc = [&](size_t bytes) {
        char* r = p;
        p += (bytes + 255) & ~(size_t)255;
        return r;
    };
    int*   bcnt  = (int*)  alloc(BMAX * 4);
    int*   bbase = (int*)  alloc(BMAX * 4);
    int*   bcur  = (int*)  alloc(BMAX * 4);
    int*   cnt   = (int*)  alloc((size_t)n * 4);
    int*   off   = (int*)  alloc((size_t)n * 4);
    float* dis   = (float*)alloc((size_t)n * 4);
    short* w2h   = (short*)alloc((size_t)D1 * D2 * 2);
    short* w2l   = (short*)alloc((size_t)D1 * D2 * 2);
    int2*  ebuf  = (int2*) alloc((size_t)e * 8);
    int2*  csr   = (int2*) alloc((size_t)e * 8);
    float* embW  = (float*)alloc((size_t)ntypes * D1 * 4);
    float* x1    = (float*)alloc((size_t)n * D1 * 4);  // also holds h2 in cols 0..63
    (void)ws_size;

    hipMemsetAsync(bcnt, 0, BMAX * 4, stream);

    // ---- bucketed CSR build ----
    bhist_k<<<512, 256, 0, stream>>>(dst, bcnt, e);
    bscan_k<<<1, BMAX, 0, stream>>>(bcnt, bbase, bcur, nb);
    bpart_k<<<(e + TILE - 1) / TILE, 256, 0, stream>>>(src, dst, bcur, ebuf, e);
    bcsr_k<<<nb, BW, 0, stream>>>(ebuf, bbase, bcnt, types, cnt, off, csr, n);
    dis_k<<<(n + 255) / 256, 256, 0, stream>>>(cnt, dis, n);
    w2prep_k<<<(D1 * D2 + 255) / 256, 256, 0, stream>>>(W2, w2h, w2l);

    // ---- layer 1: embW = emb@W1; aggregate -> x1 (relu(agg + b1)) ----
    gemm_emb_k<<<256, 128, 0, stream>>>(emb, W1, embW, ntypes);
    int nwb = (n + 3) / 4;      // one wave per node, 4 waves per block
    agg1_k<<<nwb, 256, 0, stream>>>(types, csr, off, cnt, dis, embW, b1, x1, n);

    // ---- layer 2: h2 = x1@W2 in-place (MFMA, 16 rows/wave); agg h2 -> out ----
    int ngw = (n + 15) / 16;
    gemm2_k<<<(ngw + 3) / 4, 256, 0, stream>>>(x1, w2h, w2l, n);
    agg2_k<<<nwb, 256, 0, stream>>>(csr, off, cnt, dis, x1, b2, out, n);
}

// Round 8
// 293.689 us; speedup vs baseline: 1.8084x; 1.0575x over previous
//
#include <hip/hip_runtime.h>
#include <hip/hip_bf16.h>

// GCN encoder: x = emb[types]; x1 = relu(gcnconv(x,W1,b1)); out = gcnconv(x1,W2,b2)
// gcnconv: deg[i] = indeg(i)+1 (self loop); dis = rsqrt(deg);
//          out[i] = sum_{e:dst=i} (x[src_e]@W)*dis[src]*dis[i] + (x[i]@W)*dis[i]^2 + b
//
// Strategy (round 8):
//  - Bucketed CSR build (LDS atomics only); ebuf/csr packed to ONE uint per edge
//    (src | dlocal<<17, src | type<<17) to halve partition/build/agg traffic.
//  - embW = emb @ W1 (1000x128, L2-resident): layer-1 messages gather 512B rows.
//  - agg kernels: one wave per node, zero LDS, shfl-broadcast edge loop.
//  - gemm2: MFMA 16x16x32 bf16 split-hi/lo fp32 emulation; h2 stored BF16
//    (dense [n][64]) to halve agg2's gather volume.

#define D1 128
#define D2 64
#define BSH 9            // bucket covers 512 nodes
#define BW  512
#define BMAX 256         // max buckets supported (n <= 131072)
#define TILE 2048        // edges per bpart block (8 per thread)
#define SMASK 0x1FFFF    // low 17 bits = src index (n < 131072)

typedef __attribute__((ext_vector_type(8))) short short8v;
typedef __attribute__((ext_vector_type(4))) float f32x4;

__device__ __forceinline__ short bf16_hi(float x) {
    return (short)(__float_as_uint(x) >> 16);
}
__device__ __forceinline__ float hi_f(float x) {
    return __uint_as_float(__float_as_uint(x) & 0xFFFF0000u);
}
__device__ __forceinline__ short bf16_rne(float x) {
    unsigned u = __float_as_uint(x);
    return (short)((u + 0x7FFFu + ((u >> 16) & 1u)) >> 16);
}
__device__ __forceinline__ float bf16_f(unsigned short u) {
    return __uint_as_float((unsigned)u << 16);
}

// ---- bucket histogram (LDS-aggregated) ----
__global__ __launch_bounds__(256) void bhist_k(const int* __restrict__ dst,
                                               int* __restrict__ bcnt, int e) {
    __shared__ int h[BMAX];
    if (threadIdx.x < BMAX) h[threadIdx.x] = 0;
    __syncthreads();
    int stride = gridDim.x * blockDim.x;
    for (int t = blockIdx.x * blockDim.x + threadIdx.x; t < e; t += stride)
        atomicAdd(&h[dst[t] >> BSH], 1);
    __syncthreads();
    if (threadIdx.x < BMAX && h[threadIdx.x])
        atomicAdd(&bcnt[threadIdx.x], h[threadIdx.x]);
}

// ---- bucket base scan (one block) ----
__global__ void bscan_k(const int* __restrict__ bcnt, int* __restrict__ bbase,
                        int* __restrict__ bcur, int nb) {
    __shared__ int tmp[BMAX];
    int tid = threadIdx.x;          // 256 threads
    int v = (tid < nb) ? bcnt[tid] : 0;
    tmp[tid] = v;
    __syncthreads();
    for (int s = 1; s < BMAX; s <<= 1) {
        int a = (tid >= s) ? tmp[tid - s] : 0;
        __syncthreads();
        tmp[tid] += a;
        __syncthreads();
    }
    if (tid < nb) { int ex = tmp[tid] - v; bbase[tid] = ex; bcur[tid] = ex; }
}

// ---- partition edges into bucket regions (packed uint: src | dlocal<<17) ----
__global__ __launch_bounds__(256) void bpart_k(const int* __restrict__ src,
                                               const int* __restrict__ dst,
                                               int* __restrict__ bcur,
                                               unsigned* __restrict__ ebuf, int e) {
    __shared__ int hist[BMAX];
    __shared__ int chunk[BMAX];
    __shared__ int lcur[BMAX];
    int tid = threadIdx.x;
    int base = blockIdx.x * TILE;
    if (tid < BMAX) { hist[tid] = 0; lcur[tid] = 0; }
    __syncthreads();
    unsigned p8[8];
    int b8[8];
    #pragma unroll
    for (int i = 0; i < 8; ++i) {
        int t = base + i * 256 + tid;
        if (t < e) {
            int s = src[t], d = dst[t];
            b8[i] = d >> BSH;
            p8[i] = (unsigned)s | ((unsigned)(d & (BW - 1)) << 17);
            atomicAdd(&hist[b8[i]], 1);
        } else b8[i] = -1;
    }
    __syncthreads();
    if (tid < BMAX && hist[tid]) chunk[tid] = atomicAdd(&bcur[tid], hist[tid]);
    __syncthreads();
    #pragma unroll
    for (int i = 0; i < 8; ++i) {
        if (b8[i] >= 0) {
            int r = atomicAdd(&lcur[b8[i]], 1);
            ebuf[chunk[b8[i]] + r] = p8[i];
        }
    }
}

// ---- per-bucket CSR build: LDS count + scan + cursor; emits cnt/off/csr ----
// csr entry packed: src | type<<17
__global__ __launch_bounds__(512) void bcsr_k(const unsigned* __restrict__ ebuf,
                                              const int* __restrict__ bbase,
                                              const int* __restrict__ bcnt,
                                              const int* __restrict__ types,
                                              int* __restrict__ cnt,
                                              int* __restrict__ off,
                                              unsigned* __restrict__ csr, int n) {
    __shared__ int lcnt[BW];
    __shared__ int lsc[BW];
    __shared__ int lcur[BW];
    int b = blockIdx.x;
    int d0 = b << BSH;
    int tid = threadIdx.x;
    lcnt[tid] = 0; lcur[tid] = 0;
    __syncthreads();
    int ebase = bbase[b], ecnt = bcnt[b];
    for (int t = tid; t < ecnt; t += BW)
        atomicAdd(&lcnt[ebuf[ebase + t] >> 17], 1);
    __syncthreads();
    int v = lcnt[tid];
    lsc[tid] = v;
    __syncthreads();
    for (int s = 1; s < BW; s <<= 1) {
        int a = (tid >= s) ? lsc[tid - s] : 0;
        __syncthreads();
        lsc[tid] += a;
        __syncthreads();
    }
    int ex = lsc[tid] - v;          // exclusive within bucket
    int node = d0 + tid;
    if (node < n) { cnt[node] = v; off[node] = ebase + ex; }
    __syncthreads();
    lsc[tid] = ex;
    __syncthreads();
    for (int t = tid; t < ecnt; t += BW) {
        unsigned q = ebuf[ebase + t];
        int l = q >> 17;
        int s = q & SMASK;
        int r = atomicAdd(&lcur[l], 1);
        csr[ebase + lsc[l] + r] = (unsigned)s | ((unsigned)types[s] << 17);
    }
}

__global__ void dis_k(const int* __restrict__ cnt, float* __restrict__ dis, int n) {
    int stride = gridDim.x * blockDim.x;
    for (int t = blockIdx.x * blockDim.x + threadIdx.x; t < n; t += stride)
        dis[t] = rsqrtf((float)(cnt[t] + 1));
}

// ---- W2 -> frag-ordered bf16 hi/lo tables ----
__global__ void w2prep_k(const float* __restrict__ W2,
                         short* __restrict__ w2h, short* __restrict__ w2l) {
    int t = blockIdx.x * blockDim.x + threadIdx.x;   // t = k*64 + c
    if (t >= D1 * D2) return;
    int k = t >> 6, c = t & 63;
    float v = W2[t];
    int ct = c >> 4, kb = k >> 5;
    int l = (((k >> 3) & 3) << 4) | (c & 15);
    int j = k & 7;
    int idx = (((ct << 2) | kb) * 64 + l) * 8 + j;
    w2h[idx] = bf16_hi(v);
    w2l[idx] = bf16_rne(v - hi_f(v));
}

// embW[r][j] = sum_k emb[r][k] * W1[k][j]   (ntypes x 128)
__global__ __launch_bounds__(128) void gemm_emb_k(const float* __restrict__ emb,
                                                  const float* __restrict__ W1,
                                                  float* __restrict__ embW, int ntypes) {
    __shared__ float w[D1 * D1];  // 64 KB
    for (int t = threadIdx.x; t < D1 * D1; t += 128) w[t] = W1[t];
    __syncthreads();
    int j = threadIdx.x;
    for (int r = blockIdx.x; r < ntypes; r += gridDim.x) {
        const float* er = emb + (size_t)r * D1;
        float acc = 0.f;
        #pragma unroll 8
        for (int k = 0; k < D1; ++k) acc = fmaf(er[k], w[k * D1 + j], acc);
        embW[(size_t)r * D1 + j] = acc;
    }
}

// layer-1 aggregation: ONE WAVE PER NODE. 2 sub-groups of 32 lanes; each sub
// handles one edge per iteration, lane holds float4 at feature (lane&31)*4.
__global__ __launch_bounds__(256) void agg1_k(const int* __restrict__ types,
                                              const unsigned* __restrict__ csr,
                                              const int* __restrict__ off,
                                              const int* __restrict__ cnt,
                                              const float* __restrict__ dis,
                                              const float* __restrict__ embW,
                                              const float* __restrict__ b1,
                                              float* __restrict__ x1, int n) {
    int i = (blockIdx.x * blockDim.x + threadIdx.x) >> 6;   // node = wave id
    if (i >= n) return;
    int lane = threadIdx.x & 63;
    int sub = lane >> 5;            // 0..1
    int fl = (lane & 31) << 2;      // feature base 0..124
    float disi = dis[i];
    int ti = types[i];
    int base = off[i], c = cnt[i];
    int total = c + 1;              // + self loop (virtual edge idx==c)
    float4 acc = make_float4(0.f, 0.f, 0.f, 0.f);
    for (int cb = 0; cb < total; cb += 64) {
        int idx = cb + lane;
        int t_l = 0;
        float c_l = 0.f;
        if (idx < c) {
            unsigned q = csr[base + idx];
            t_l = q >> 17;
            c_l = disi * dis[q & SMASK];
        } else if (idx == c) {
            t_l = ti;
            c_l = disi * disi;      // self loop
        }
        int m = min(64, total - cb);
        for (int k0 = 0; k0 < m; k0 += 2) {
            int k = k0 + sub;       // <= 63 always
            int t = __shfl(t_l, k);
            float cf = __shfl(c_l, k);  // 0 for out-of-range k
            float4 v = *(const float4*)(embW + (size_t)t * D1 + fl);
            acc.x = fmaf(v.x, cf, acc.x);
            acc.y = fmaf(v.y, cf, acc.y);
            acc.z = fmaf(v.z, cf, acc.z);
            acc.w = fmaf(v.w, cf, acc.w);
        }
    }
    acc.x += __shfl_xor(acc.x, 32);
    acc.y += __shfl_xor(acc.y, 32);
    acc.z += __shfl_xor(acc.z, 32);
    acc.w += __shfl_xor(acc.w, 32);
    if (sub == 0) {
        float4 bv = ((const float4*)b1)[lane & 31];
        acc.x = fmaxf(acc.x + bv.x, 0.f);
        acc.y = fmaxf(acc.y + bv.y, 0.f);
        acc.z = fmaxf(acc.z + bv.z, 0.f);
        acc.w = fmaxf(acc.w + bv.w, 0.f);
        ((float4*)(x1 + (size_t)i * D1))[lane & 31] = acc;
    }
}

// h2 = x1 @ W2 via MFMA -> BF16 dense [n][64].
// One wave per 16 rows. Split-bf16 fp32 emulation: xh@Wh + xl@Wh + xh@Wl.
__global__ __launch_bounds__(256) void gemm2_k(const float* __restrict__ x1,
                                               const short* __restrict__ w2h,
                                               const short* __restrict__ w2l,
                                               unsigned short* __restrict__ h2b, int n) {
    int gw = (blockIdx.x * blockDim.x + threadIdx.x) >> 6;  // global wave id
    int lane = threadIdx.x & 63;
    int r0 = gw << 4;
    if (r0 >= n) return;
    int row = r0 + (lane & 15);
    int kq = lane >> 4;             // 0..3
    bool ok = row < n;
    const float* xr = x1 + (size_t)row * D1 + kq * 8;
    short8v ah[4], al[4];
    #pragma unroll
    for (int kb = 0; kb < 4; ++kb) {
        float4 v0, v1;
        if (ok) {
            v0 = *(const float4*)(xr + kb * 32);
            v1 = *(const float4*)(xr + kb * 32 + 4);
        } else {
            v0 = make_float4(0.f, 0.f, 0.f, 0.f);
            v1 = v0;
        }
        float xv[8] = {v0.x, v0.y, v0.z, v0.w, v1.x, v1.y, v1.z, v1.w};
        #pragma unroll
        for (int j = 0; j < 8; ++j) {
            ah[kb][j] = bf16_hi(xv[j]);
            al[kb][j] = bf16_rne(xv[j] - hi_f(xv[j]));
        }
    }
    const short8v* w2hv = (const short8v*)w2h;
    const short8v* w2lv = (const short8v*)w2l;
    #pragma unroll
    for (int ct = 0; ct < 4; ++ct) {
        f32x4 acc = {0.f, 0.f, 0.f, 0.f};
        #pragma unroll
        for (int kb = 0; kb < 4; ++kb) {
            short8v bh = w2hv[(ct * 4 + kb) * 64 + lane];
            short8v bl = w2lv[(ct * 4 + kb) * 64 + lane];
            acc = __builtin_amdgcn_mfma_f32_16x16x32_bf16(ah[kb], bh, acc, 0, 0, 0);
            acc = __builtin_amdgcn_mfma_f32_16x16x32_bf16(al[kb], bh, acc, 0, 0, 0);
            acc = __builtin_amdgcn_mfma_f32_16x16x32_bf16(ah[kb], bl, acc, 0, 0, 0);
        }
        #pragma unroll
        for (int v = 0; v < 4; ++v) {
            int orow = r0 + (lane >> 4) * 4 + v;
            if (orow < n)
                h2b[(size_t)orow * D2 + ct * 16 + (lane & 15)] =
                    (unsigned short)bf16_rne(acc[v]);
        }
    }
}

// layer-2 aggregation: ONE WAVE PER NODE. 4 sub-groups of 16 lanes; each sub
// handles one edge per iteration, lane holds 4 bf16 at feature (lane&15)*4.
__global__ __launch_bounds__(256) void agg2_k(const unsigned* __restrict__ csr,
                                              const int* __restrict__ off,
                                              const int* __restrict__ cnt,
                                              const float* __restrict__ dis,
                                              const unsigned short* __restrict__ h2b,
                                              const float* __restrict__ b2,
                                              float* __restrict__ out, int n) {
    int i = (blockIdx.x * blockDim.x + threadIdx.x) >> 6;   // node = wave id
    if (i >= n) return;
    int lane = threadIdx.x & 63;
    int sub = lane >> 4;            // 0..3
    int fl = (lane & 15) << 2;      // feature base 0..60
    float disi = dis[i];
    int base = off[i], c = cnt[i];
    int total = c + 1;              // + self loop (virtual edge idx==c)
    float4 acc = make_float4(0.f, 0.f, 0.f, 0.f);
    for (int cb = 0; cb < total; cb += 64) {
        int idx = cb + lane;
        int s_l = i;
        float c_l = 0.f;
        if (idx < c) {
            unsigned q = csr[base + idx];
            s_l = q & SMASK;
            c_l = disi * dis[s_l];
        } else if (idx == c) {
            c_l = disi * disi;      // self loop
        }
        int m = min(64, total - cb);
        for (int k0 = 0; k0 < m; k0 += 4) {
            int k = k0 + sub;       // <= 63 always
            int s = __shfl(s_l, k);
            float cf = __shfl(c_l, k);  // 0 for out-of-range k
            ushort4 hv = *(const ushort4*)(h2b + (size_t)s * D2 + fl);
            acc.x = fmaf(bf16_f(hv.x), cf, acc.x);
            acc.y = fmaf(bf16_f(hv.y), cf, acc.y);
            acc.z = fmaf(bf16_f(hv.z), cf, acc.z);
            acc.w = fmaf(bf16_f(hv.w), cf, acc.w);
        }
    }
    acc.x += __shfl_xor(acc.x, 16);
    acc.y += __shfl_xor(acc.y, 16);
    acc.z += __shfl_xor(acc.z, 16);
    acc.w += __shfl_xor(acc.w, 16);
    acc.x += __shfl_xor(acc.x, 32);
    acc.y += __shfl_xor(acc.y, 32);
    acc.z += __shfl_xor(acc.z, 32);
    acc.w += __shfl_xor(acc.w, 32);
    if (sub == 0) {
        float4 bv = ((const float4*)b2)[lane & 15];
        acc.x += bv.x;
        acc.y += bv.y;
        acc.z += bv.z;
        acc.w += bv.w;
        ((float4*)(out + (size_t)i * D2))[lane & 15] = acc;
    }
}

extern "C" void kernel_launch(void* const* d_in, const int* in_sizes, int n_in,
                              void* d_out, int out_size, void* d_ws, size_t ws_size,
                              hipStream_t stream) {
    const int* types = (const int*)d_in[0];
    const int* edges = (const int*)d_in[1];
    const float* emb = (const float*)d_in[2];
    const float* W1  = (const float*)d_in[3];
    const float* b1  = (const float*)d_in[4];
    const float* W2  = (const float*)d_in[5];
    const float* b2  = (const float*)d_in[6];
    float* out = (float*)d_out;

    const int n = in_sizes[0];
    const int e = in_sizes[1] / 2;
    const int ntypes = in_sizes[2] / D1;
    const int* src = edges;
    const int* dst = edges + e;
    const int nb = (n + BW - 1) >> BSH;   // 196 buckets for n=100000 (<= BMAX)

    // ---- workspace layout (256B aligned slabs) ----
    char* p = (char*)d_ws;
    auto alloc = [&](size_t bytes) {
        char* r = p;
        p += (bytes + 255) & ~(size_t)255;
        return r;
    };
    int*      bcnt  = (int*)      alloc(BMAX * 4);
    int*      bbase = (int*)      alloc(BMAX * 4);
    int*      bcur  = (int*)      alloc(BMAX * 4);
    int*      cnt   = (int*)      alloc((size_t)n * 4);
    int*      off   = (int*)      alloc((size_t)n * 4);
    float*    dis   = (float*)    alloc((size_t)n * 4);
    short*    w2h   = (short*)    alloc((size_t)D1 * D2 * 2);
    short*    w2l   = (short*)    alloc((size_t)D1 * D2 * 2);
    unsigned* ebuf  = (unsigned*) alloc((size_t)e * 4);
    unsigned* csr   = (unsigned*) alloc((size_t)e * 4);
    float*    embW  = (float*)    alloc((size_t)ntypes * D1 * 4);
    float*    x1    = (float*)    alloc((size_t)n * D1 * 4);
    unsigned short* h2b = (unsigned short*)alloc((size_t)n * D2 * 2);
    (void)ws_size;

    hipMemsetAsync(bcnt, 0, BMAX * 4, stream);

    // ---- bucketed CSR build ----
    bhist_k<<<512, 256, 0, stream>>>(dst, bcnt, e);
    bscan_k<<<1, BMAX, 0, stream>>>(bcnt, bbase, bcur, nb);
    bpart_k<<<(e + TILE - 1) / TILE, 256, 0, stream>>>(src, dst, bcur, ebuf, e);
    bcsr_k<<<nb, BW, 0, stream>>>(ebuf, bbase, bcnt, types, cnt, off, csr, n);
    dis_k<<<(n + 255) / 256, 256, 0, stream>>>(cnt, dis, n);
    w2prep_k<<<(D1 * D2 + 255) / 256, 256, 0, stream>>>(W2, w2h, w2l);

    // ---- layer 1: embW = emb@W1; aggregate -> x1 (relu(agg + b1)) ----
    gemm_emb_k<<<256, 128, 0, stream>>>(emb, W1, embW, ntypes);
    int nwb = (n + 3) / 4;      // one wave per node, 4 waves per block
    agg1_k<<<nwb, 256, 0, stream>>>(types, csr, off, cnt, dis, embW, b1, x1, n);

    // ---- layer 2: h2 = x1@W2 (MFMA -> bf16); aggregate h2 -> out ----
    int ngw = (n + 15) / 16;
    gemm2_k<<<(ngw + 3) / 4, 256, 0, stream>>>(x1, w2h, w2l, h2b, n);
    agg2_k<<<nwb, 256, 0, stream>>>(csr, off, cnt, dis, h2b, b2, out, n);
}

// Round 9
// 283.210 us; speedup vs baseline: 1.8753x; 1.0370x over previous
//
#include <hip/hip_runtime.h>
#include <hip/hip_bf16.h>

// GCN encoder: x = emb[types]; x1 = relu(gcnconv(x,W1,b1)); out = gcnconv(x1,W2,b2)
// gcnconv: deg[i] = indeg(i)+1 (self loop); dis = rsqrt(deg);
//          out[i] = sum_{e:dst=i} (x[src_e]@W)*dis[src]*dis[i] + (x[i]@W)*dis[i]^2 + b
//
// Strategy (round 9):
//  - Bucketed CSR build, split: bcsr_count (cnt/off/dis) then bcsr_fill writes
//    int2 {src|type<<17, coef} with coef = dis[dst]*dis[src] PRE-MULTIPLIED
//    (fp32 exact) -> agg preloads are one coalesced stream, no gather chains.
//  - agg kernels: one wave per node; edge loop UNROLLED x4 (4 row-loads in
//    flight, 2 accumulators) to break the shfl->load latency serialization.
//  - gemm2: MFMA 16x16x32 bf16 split-hi/lo fp32 emulation; h2 stored bf16.

#define D1 128
#define D2 64
#define BSH 9            // bucket covers 512 nodes
#define BW  512
#define BMAX 256         // max buckets supported (n <= 131072)
#define TILE 2048        // edges per bpart block (8 per thread)
#define SMASK 0x1FFFF    // low 17 bits = src index (n < 131072)

typedef __attribute__((ext_vector_type(8))) short short8v;
typedef __attribute__((ext_vector_type(4))) float f32x4;

__device__ __forceinline__ short bf16_hi(float x) {
    return (short)(__float_as_uint(x) >> 16);
}
__device__ __forceinline__ float hi_f(float x) {
    return __uint_as_float(__float_as_uint(x) & 0xFFFF0000u);
}
__device__ __forceinline__ short bf16_rne(float x) {
    unsigned u = __float_as_uint(x);
    return (short)((u + 0x7FFFu + ((u >> 16) & 1u)) >> 16);
}
__device__ __forceinline__ float bf16_f(unsigned short u) {
    return __uint_as_float((unsigned)u << 16);
}

// ---- bucket histogram (LDS-aggregated) ----
__global__ __launch_bounds__(256) void bhist_k(const int* __restrict__ dst,
                                               int* __restrict__ bcnt, int e) {
    __shared__ int h[BMAX];
    if (threadIdx.x < BMAX) h[threadIdx.x] = 0;
    __syncthreads();
    int stride = gridDim.x * blockDim.x;
    for (int t = blockIdx.x * blockDim.x + threadIdx.x; t < e; t += stride)
        atomicAdd(&h[dst[t] >> BSH], 1);
    __syncthreads();
    if (threadIdx.x < BMAX && h[threadIdx.x])
        atomicAdd(&bcnt[threadIdx.x], h[threadIdx.x]);
}

// ---- bucket base scan (one block) ----
__global__ void bscan_k(const int* __restrict__ bcnt, int* __restrict__ bbase,
                        int* __restrict__ bcur, int nb) {
    __shared__ int tmp[BMAX];
    int tid = threadIdx.x;          // 256 threads
    int v = (tid < nb) ? bcnt[tid] : 0;
    tmp[tid] = v;
    __syncthreads();
    for (int s = 1; s < BMAX; s <<= 1) {
        int a = (tid >= s) ? tmp[tid - s] : 0;
        __syncthreads();
        tmp[tid] += a;
        __syncthreads();
    }
    if (tid < nb) { int ex = tmp[tid] - v; bbase[tid] = ex; bcur[tid] = ex; }
}

// ---- partition edges into bucket regions (packed uint: src | dlocal<<17) ----
__global__ __launch_bounds__(256) void bpart_k(const int* __restrict__ src,
                                               const int* __restrict__ dst,
                                               int* __restrict__ bcur,
                                               unsigned* __restrict__ ebuf, int e) {
    __shared__ int hist[BMAX];
    __shared__ int chunk[BMAX];
    __shared__ int lcur[BMAX];
    int tid = threadIdx.x;
    int base = blockIdx.x * TILE;
    if (tid < BMAX) { hist[tid] = 0; lcur[tid] = 0; }
    __syncthreads();
    unsigned p8[8];
    int b8[8];
    #pragma unroll
    for (int i = 0; i < 8; ++i) {
        int t = base + i * 256 + tid;
        if (t < e) {
            int s = src[t], d = dst[t];
            b8[i] = d >> BSH;
            p8[i] = (unsigned)s | ((unsigned)(d & (BW - 1)) << 17);
            atomicAdd(&hist[b8[i]], 1);
        } else b8[i] = -1;
    }
    __syncthreads();
    if (tid < BMAX && hist[tid]) chunk[tid] = atomicAdd(&bcur[tid], hist[tid]);
    __syncthreads();
    #pragma unroll
    for (int i = 0; i < 8; ++i) {
        if (b8[i] >= 0) {
            int r = atomicAdd(&lcur[b8[i]], 1);
            ebuf[chunk[b8[i]] + r] = p8[i];
        }
    }
}

// ---- per-bucket count: cnt/off/dis (dis = rsqrt(indeg+1) born with cnt) ----
__global__ __launch_bounds__(512) void bcsr_count_k(const unsigned* __restrict__ ebuf,
                                                    const int* __restrict__ bbase,
                                                    const int* __restrict__ bcnt,
                                                    int* __restrict__ cnt,
                                                    int* __restrict__ off,
                                                    float* __restrict__ dis, int n) {
    __shared__ int lcnt[BW];
    __shared__ int lsc[BW];
    int b = blockIdx.x;
    int d0 = b << BSH;
    int tid = threadIdx.x;
    lcnt[tid] = 0;
    __syncthreads();
    int ebase = bbase[b], ecnt = bcnt[b];
    for (int t = tid; t < ecnt; t += BW)
        atomicAdd(&lcnt[ebuf[ebase + t] >> 17], 1);
    __syncthreads();
    int v = lcnt[tid];
    lsc[tid] = v;
    __syncthreads();
    for (int s = 1; s < BW; s <<= 1) {
        int a = (tid >= s) ? lsc[tid - s] : 0;
        __syncthreads();
        lsc[tid] += a;
        __syncthreads();
    }
    int node = d0 + tid;
    if (node < n) {
        cnt[node] = v;
        off[node] = ebase + lsc[tid] - v;
        dis[node] = rsqrtf((float)(v + 1));
    }
}

// ---- per-bucket fill: csr_p = {src | type<<17, coef = dis[dst]*dis[src]} ----
__global__ __launch_bounds__(512) void bcsr_fill_k(const unsigned* __restrict__ ebuf,
                                                   const int* __restrict__ bbase,
                                                   const int* __restrict__ bcnt,
                                                   const int* __restrict__ off,
                                                   const float* __restrict__ dis,
                                                   const int* __restrict__ types,
                                                   int2* __restrict__ csr_p, int n) {
    __shared__ int loff[BW];
    __shared__ float ldis[BW];
    __shared__ int lcur[BW];
    int b = blockIdx.x;
    int d0 = b << BSH;
    int tid = threadIdx.x;
    int node = d0 + tid;
    lcur[tid] = 0;
    if (node < n) { loff[tid] = off[node]; ldis[tid] = dis[node]; }
    __syncthreads();
    int ebase = bbase[b], ecnt = bcnt[b];
    for (int t = tid; t < ecnt; t += BW) {
        unsigned q = ebuf[ebase + t];
        int l = q >> 17;
        int s = q & SMASK;
        int r = atomicAdd(&lcur[l], 1);
        float coef = ldis[l] * dis[s];
        csr_p[loff[l] + r] = make_int2(s | (types[s] << 17), __float_as_int(coef));
    }
}

// ---- W2 -> frag-ordered bf16 hi/lo tables ----
__global__ void w2prep_k(const float* __restrict__ W2,
                         short* __restrict__ w2h, short* __restrict__ w2l) {
    int t = blockIdx.x * blockDim.x + threadIdx.x;   // t = k*64 + c
    if (t >= D1 * D2) return;
    int k = t >> 6, c = t & 63;
    float v = W2[t];
    int ct = c >> 4, kb = k >> 5;
    int l = (((k >> 3) & 3) << 4) | (c & 15);
    int j = k & 7;
    int idx = (((ct << 2) | kb) * 64 + l) * 8 + j;
    w2h[idx] = bf16_hi(v);
    w2l[idx] = bf16_rne(v - hi_f(v));
}

// embW[r][j] = sum_k emb[r][k] * W1[k][j]   (ntypes x 128)
__global__ __launch_bounds__(128) void gemm_emb_k(const float* __restrict__ emb,
                                                  const float* __restrict__ W1,
                                                  float* __restrict__ embW, int ntypes) {
    __shared__ float w[D1 * D1];  // 64 KB
    for (int t = threadIdx.x; t < D1 * D1; t += 128) w[t] = W1[t];
    __syncthreads();
    int j = threadIdx.x;
    for (int r = blockIdx.x; r < ntypes; r += gridDim.x) {
        const float* er = emb + (size_t)r * D1;
        float acc = 0.f;
        #pragma unroll 8
        for (int k = 0; k < D1; ++k) acc = fmaf(er[k], w[k * D1 + j], acc);
        embW[(size_t)r * D1 + j] = acc;
    }
}

// layer-1 aggregation: ONE WAVE PER NODE, 2 sub-groups of 32 lanes, edge loop
// unrolled x4 (4 independent 512B row loads in flight, 2 accumulators).
__global__ __launch_bounds__(256) void agg1_k(const int* __restrict__ types,
                                              const int2* __restrict__ csr_p,
                                              const int* __restrict__ off,
                                              const int* __restrict__ cnt,
                                              const float* __restrict__ dis,
                                              const float* __restrict__ embW,
                                              const float* __restrict__ b1,
                                              float* __restrict__ x1, int n) {
    int i = (blockIdx.x * blockDim.x + threadIdx.x) >> 6;   // node = wave id
    if (i >= n) return;
    int lane = threadIdx.x & 63;
    int sub = lane >> 5;            // 0..1
    int fl = (lane & 31) << 2;      // feature base 0..124
    float disi = dis[i];
    int base = off[i], c = cnt[i];
    int total = c + 1;              // + self loop (virtual edge idx==c)
    float4 a0 = make_float4(0.f, 0.f, 0.f, 0.f);
    float4 a1 = make_float4(0.f, 0.f, 0.f, 0.f);
    for (int cbk = 0; cbk < total; cbk += 64) {
        int idx = cbk + lane;
        int t_l = 0;
        float c_l = 0.f;
        if (idx < c) {
            int2 q = csr_p[base + idx];
            t_l = q.x >> 17;
            c_l = __int_as_float(q.y);          // pre-multiplied coef
        } else if (idx == c) {
            t_l = types[i];
            c_l = disi * disi;                  // self loop
        }
        int m = min(64, total - cbk);
        int k0 = 0;
        for (; k0 + 8 <= m; k0 += 8) {          // 4 edges per sub per iter
            int   tA = __shfl(t_l, k0 + sub);
            float cA = __shfl(c_l, k0 + sub);
            int   tB = __shfl(t_l, k0 + 2 + sub);
            float cB = __shfl(c_l, k0 + 2 + sub);
            int   tC = __shfl(t_l, k0 + 4 + sub);
            float cC = __shfl(c_l, k0 + 4 + sub);
            int   tD = __shfl(t_l, k0 + 6 + sub);
            float cD = __shfl(c_l, k0 + 6 + sub);
            float4 vA = *(const float4*)(embW + (size_t)tA * D1 + fl);
            float4 vB = *(const float4*)(embW + (size_t)tB * D1 + fl);
            float4 vC = *(const float4*)(embW + (size_t)tC * D1 + fl);
            float4 vD = *(const float4*)(embW + (size_t)tD * D1 + fl);
            a0.x = fmaf(vA.x, cA, a0.x); a0.y = fmaf(vA.y, cA, a0.y);
            a0.z = fmaf(vA.z, cA, a0.z); a0.w = fmaf(vA.w, cA, a0.w);
            a1.x = fmaf(vB.x, cB, a1.x); a1.y = fmaf(vB.y, cB, a1.y);
            a1.z = fmaf(vB.z, cB, a1.z); a1.w = fmaf(vB.w, cB, a1.w);
            a0.x = fmaf(vC.x, cC, a0.x); a0.y = fmaf(vC.y, cC, a0.y);
            a0.z = fmaf(vC.z, cC, a0.z); a0.w = fmaf(vC.w, cC, a0.w);
            a1.x = fmaf(vD.x, cD, a1.x); a1.y = fmaf(vD.y, cD, a1.y);
            a1.z = fmaf(vD.z, cD, a1.z); a1.w = fmaf(vD.w, cD, a1.w);
        }
        for (; k0 < m; k0 += 2) {
            int k = k0 + sub;                   // <= 63 always
            int   t = __shfl(t_l, k);
            float cf = __shfl(c_l, k);          // 0 for out-of-range k
            float4 v = *(const float4*)(embW + (size_t)t * D1 + fl);
            a0.x = fmaf(v.x, cf, a0.x); a0.y = fmaf(v.y, cf, a0.y);
            a0.z = fmaf(v.z, cf, a0.z); a0.w = fmaf(v.w, cf, a0.w);
        }
    }
    float4 acc = make_float4(a0.x + a1.x, a0.y + a1.y, a0.z + a1.z, a0.w + a1.w);
    acc.x += __shfl_xor(acc.x, 32);
    acc.y += __shfl_xor(acc.y, 32);
    acc.z += __shfl_xor(acc.z, 32);
    acc.w += __shfl_xor(acc.w, 32);
    if (sub == 0) {
        float4 bv = ((const float4*)b1)[lane & 31];
        acc.x = fmaxf(acc.x + bv.x, 0.f);
        acc.y = fmaxf(acc.y + bv.y, 0.f);
        acc.z = fmaxf(acc.z + bv.z, 0.f);
        acc.w = fmaxf(acc.w + bv.w, 0.f);
        ((float4*)(x1 + (size_t)i * D1))[lane & 31] = acc;
    }
}

// h2 = x1 @ W2 via MFMA -> BF16 dense [n][64].
// One wave per 16 rows. Split-bf16 fp32 emulation: xh@Wh + xl@Wh + xh@Wl.
__global__ __launch_bounds__(256) void gemm2_k(const float* __restrict__ x1,
                                               const short* __restrict__ w2h,
                                               const short* __restrict__ w2l,
                                               unsigned short* __restrict__ h2b, int n) {
    int gw = (blockIdx.x * blockDim.x + threadIdx.x) >> 6;  // global wave id
    int lane = threadIdx.x & 63;
    int r0 = gw << 4;
    if (r0 >= n) return;
    int row = r0 + (lane & 15);
    int kq = lane >> 4;             // 0..3
    bool ok = row < n;
    const float* xr = x1 + (size_t)row * D1 + kq * 8;
    short8v ah[4], al[4];
    #pragma unroll
    for (int kb = 0; kb < 4; ++kb) {
        float4 v0, v1;
        if (ok) {
            v0 = *(const float4*)(xr + kb * 32);
            v1 = *(const float4*)(xr + kb * 32 + 4);
        } else {
            v0 = make_float4(0.f, 0.f, 0.f, 0.f);
            v1 = v0;
        }
        float xv[8] = {v0.x, v0.y, v0.z, v0.w, v1.x, v1.y, v1.z, v1.w};
        #pragma unroll
        for (int j = 0; j < 8; ++j) {
            ah[kb][j] = bf16_hi(xv[j]);
            al[kb][j] = bf16_rne(xv[j] - hi_f(xv[j]));
        }
    }
    const short8v* w2hv = (const short8v*)w2h;
    const short8v* w2lv = (const short8v*)w2l;
    #pragma unroll
    for (int ct = 0; ct < 4; ++ct) {
        f32x4 acc = {0.f, 0.f, 0.f, 0.f};
        #pragma unroll
        for (int kb = 0; kb < 4; ++kb) {
            short8v bh = w2hv[(ct * 4 + kb) * 64 + lane];
            short8v bl = w2lv[(ct * 4 + kb) * 64 + lane];
            acc = __builtin_amdgcn_mfma_f32_16x16x32_bf16(ah[kb], bh, acc, 0, 0, 0);
            acc = __builtin_amdgcn_mfma_f32_16x16x32_bf16(al[kb], bh, acc, 0, 0, 0);
            acc = __builtin_amdgcn_mfma_f32_16x16x32_bf16(ah[kb], bl, acc, 0, 0, 0);
        }
        #pragma unroll
        for (int v = 0; v < 4; ++v) {
            int orow = r0 + (lane >> 4) * 4 + v;
            if (orow < n)
                h2b[(size_t)orow * D2 + ct * 16 + (lane & 15)] =
                    (unsigned short)bf16_rne(acc[v]);
        }
    }
}

// layer-2 aggregation: ONE WAVE PER NODE, 4 sub-groups of 16 lanes, edge loop
// unrolled x4 (4 independent 128B bf16 row loads in flight, 2 accumulators).
__global__ __launch_bounds__(256) void agg2_k(const int2* __restrict__ csr_p,
                                              const int* __restrict__ off,
                                              const int* __restrict__ cnt,
                                              const float* __restrict__ dis,
                                              const unsigned short* __restrict__ h2b,
                                              const float* __restrict__ b2,
                                              float* __restrict__ out, int n) {
    int i = (blockIdx.x * blockDim.x + threadIdx.x) >> 6;   // node = wave id
    if (i >= n) return;
    int lane = threadIdx.x & 63;
    int sub = lane >> 4;            // 0..3
    int fl = (lane & 15) << 2;      // feature base 0..60
    float disi = dis[i];
    int base = off[i], c = cnt[i];
    int total = c + 1;              // + self loop (virtual edge idx==c)
    float4 a0 = make_float4(0.f, 0.f, 0.f, 0.f);
    float4 a1 = make_float4(0.f, 0.f, 0.f, 0.f);
    for (int cbk = 0; cbk < total; cbk += 64) {
        int idx = cbk + lane;
        int s_l = i;
        float c_l = 0.f;
        if (idx < c) {
            int2 q = csr_p[base + idx];
            s_l = q.x & SMASK;
            c_l = __int_as_float(q.y);          // pre-multiplied coef
        } else if (idx == c) {
            c_l = disi * disi;                  // self loop
        }
        int m = min(64, total - cbk);
        int k0 = 0;
        for (; k0 + 16 <= m; k0 += 16) {        // 4 edges per sub per iter
            int   sA = __shfl(s_l, k0 + sub);
            float cA = __shfl(c_l, k0 + sub);
            int   sB = __shfl(s_l, k0 + 4 + sub);
            float cB = __shfl(c_l, k0 + 4 + sub);
            int   sC = __shfl(s_l, k0 + 8 + sub);
            float cC = __shfl(c_l, k0 + 8 + sub);
            int   sD = __shfl(s_l, k0 + 12 + sub);
            float cD = __shfl(c_l, k0 + 12 + sub);
            ushort4 hA = *(const ushort4*)(h2b + (size_t)sA * D2 + fl);
            ushort4 hB = *(const ushort4*)(h2b + (size_t)sB * D2 + fl);
            ushort4 hC = *(const ushort4*)(h2b + (size_t)sC * D2 + fl);
            ushort4 hD = *(const ushort4*)(h2b + (size_t)sD * D2 + fl);
            a0.x = fmaf(bf16_f(hA.x), cA, a0.x); a0.y = fmaf(bf16_f(hA.y), cA, a0.y);
            a0.z = fmaf(bf16_f(hA.z), cA, a0.z); a0.w = fmaf(bf16_f(hA.w), cA, a0.w);
            a1.x = fmaf(bf16_f(hB.x), cB, a1.x); a1.y = fmaf(bf16_f(hB.y), cB, a1.y);
            a1.z = fmaf(bf16_f(hB.z), cB, a1.z); a1.w = fmaf(bf16_f(hB.w), cB, a1.w);
            a0.x = fmaf(bf16_f(hC.x), cC, a0.x); a0.y = fmaf(bf16_f(hC.y), cC, a0.y);
            a0.z = fmaf(bf16_f(hC.z), cC, a0.z); a0.w = fmaf(bf16_f(hC.w), cC, a0.w);
            a1.x = fmaf(bf16_f(hD.x), cD, a1.x); a1.y = fmaf(bf16_f(hD.y), cD, a1.y);
            a1.z = fmaf(bf16_f(hD.z), cD, a1.z); a1.w = fmaf(bf16_f(hD.w), cD, a1.w);
        }
        for (; k0 < m; k0 += 4) {
            int k = k0 + sub;                   // <= 63 always
            int   s = __shfl(s_l, k);
            float cf = __shfl(c_l, k);          // 0 for out-of-range k
            ushort4 hv = *(const ushort4*)(h2b + (size_t)s * D2 + fl);
            a0.x = fmaf(bf16_f(hv.x), cf, a0.x); a0.y = fmaf(bf16_f(hv.y), cf, a0.y);
            a0.z = fmaf(bf16_f(hv.z), cf, a0.z); a0.w = fmaf(bf16_f(hv.w), cf, a0.w);
        }
    }
    float4 acc = make_float4(a0.x + a1.x, a0.y + a1.y, a0.z + a1.z, a0.w + a1.w);
    acc.x += __shfl_xor(acc.x, 16);
    acc.y += __shfl_xor(acc.y, 16);
    acc.z += __shfl_xor(acc.z, 16);
    acc.w += __shfl_xor(acc.w, 16);
    acc.x += __shfl_xor(acc.x, 32);
    acc.y += __shfl_xor(acc.y, 32);
    acc.z += __shfl_xor(acc.z, 32);
    acc.w += __shfl_xor(acc.w, 32);
    if (sub == 0) {
        float4 bv = ((const float4*)b2)[lane & 15];
        acc.x += bv.x;
        acc.y += bv.y;
        acc.z += bv.z;
        acc.w += bv.w;
        ((float4*)(out + (size_t)i * D2))[lane & 15] = acc;
    }
}

extern "C" void kernel_launch(void* const* d_in, const int* in_sizes, int n_in,
                              void* d_out, int out_size, void* d_ws, size_t ws_size,
                              hipStream_t stream) {
    const int* types = (const int*)d_in[0];
    const int* edges = (const int*)d_in[1];
    const float* emb = (const float*)d_in[2];
    const float* W1  = (const float*)d_in[3];
    const float* b1  = (const float*)d_in[4];
    const float* W2  = (const float*)d_in[5];
    const float* b2  = (const float*)d_in[6];
    float* out = (float*)d_out;

    const int n = in_sizes[0];
    const int e = in_sizes[1] / 2;
    const int ntypes = in_sizes[2] / D1;
    const int* src = edges;
    const int* dst = edges + e;
    const int nb = (n + BW - 1) >> BSH;   // 196 buckets for n=100000 (<= BMAX)

    // ---- workspace layout (256B aligned slabs) ----
    char* p = (char*)d_ws;
    auto alloc = [&](size_t bytes) {
        char* r = p;
        p += (bytes + 255) & ~(size_t)255;
        return r;
    };
    int*      bcnt  = (int*)      alloc(BMAX * 4);
    int*      bbase = (int*)      alloc(BMAX * 4);
    int*      bcur  = (int*)      alloc(BMAX * 4);
    int*      cnt   = (int*)      alloc((size_t)n * 4);
    int*      off   = (int*)      alloc((size_t)n * 4);
    float*    dis   = (float*)    alloc((size_t)n * 4);
    short*    w2h   = (short*)    alloc((size_t)D1 * D2 * 2);
    short*    w2l   = (short*)    alloc((size_t)D1 * D2 * 2);
    unsigned* ebuf  = (unsigned*) alloc((size_t)e * 4);
    int2*     csr_p = (int2*)     alloc((size_t)e * 8);
    float*    embW  = (float*)    alloc((size_t)ntypes * D1 * 4);
    float*    x1    = (float*)    alloc((size_t)n * D1 * 4);
    unsigned short* h2b = (unsigned short*)alloc((size_t)n * D2 * 2);
    (void)ws_size;

    hipMemsetAsync(bcnt, 0, BMAX * 4, stream);

    // ---- bucketed CSR build ----
    bhist_k<<<512, 256, 0, stream>>>(dst, bcnt, e);
    bscan_k<<<1, BMAX, 0, stream>>>(bcnt, bbase, bcur, nb);
    bpart_k<<<(e + TILE - 1) / TILE, 256, 0, stream>>>(src, dst, bcur, ebuf, e);
    bcsr_count_k<<<nb, BW, 0, stream>>>(ebuf, bbase, bcnt, cnt, off, dis, n);
    bcsr_fill_k<<<nb, BW, 0, stream>>>(ebuf, bbase, bcnt, off, dis, types, csr_p, n);
    w2prep_k<<<(D1 * D2 + 255) / 256, 256, 0, stream>>>(W2, w2h, w2l);

    // ---- layer 1: embW = emb@W1; aggregate -> x1 (relu(agg + b1)) ----
    gemm_emb_k<<<256, 128, 0, stream>>>(emb, W1, embW, ntypes);
    int nwb = (n + 3) / 4;      // one wave per node, 4 waves per block
    agg1_k<<<nwb, 256, 0, stream>>>(types, csr_p, off, cnt, dis, embW, b1, x1, n);

    // ---- layer 2: h2 = x1@W2 (MFMA -> bf16); aggregate h2 -> out ----
    int ngw = (n + 15) / 16;
    gemm2_k<<<(ngw + 3) / 4, 256, 0, stream>>>(x1, w2h, w2l, h2b, n);
    agg2_k<<<nwb, 256, 0, stream>>>(csr_p, off, cnt, dis, h2b, b2, out, n);
}